// Round 1
// baseline (94.713 us; speedup 1.0000x reference)
//
#include <hip/hip_runtime.h>
#include <math.h>

#define DIM 128
#define P_POS 3
#define N_NEG 63

__device__ __forceinline__ float wave_reduce_sum(float v) {
#pragma unroll
    for (int off = 32; off > 0; off >>= 1)
        v += __shfl_xor(v, off, 64);
    return v;
}

// One wave per row: inverse L2 norm of each ids_fut row.
__global__ __launch_bounds__(256) void norms_kernel(const float* __restrict__ fut,
                                                    float* __restrict__ rnf,
                                                    int nrows) {
    int wave = threadIdx.x >> 6;
    int lane = threadIdx.x & 63;
    int row = blockIdx.x * 4 + wave;
    if (row >= nrows) return;
    const float2 v = *reinterpret_cast<const float2*>(fut + (size_t)row * DIM + lane * 2);
    float ss = wave_reduce_sum(fmaf(v.x, v.x, v.y * v.y));
    if (lane == 0) rnf[row] = (ss > 0.f) ? rsqrtf(ss) : 0.f;
}

// One wave per anchor; 4 anchors per 256-thread block.
__global__ __launch_bounds__(256) void idloss_kernel(
    const float* __restrict__ fut, const float* __restrict__ hist,
    const int* __restrict__ anchor_idx, const int* __restrict__ pos_idx,
    const int* __restrict__ neg_idx, const float* __restrict__ rnf,
    float* __restrict__ partials) {
    __shared__ float smem[4];
    int wave = threadIdx.x >> 6;
    int lane = threadIdx.x & 63;
    int m = blockIdx.x * 4 + wave;

    const float2 a =
        *reinterpret_cast<const float2*>(hist + (size_t)anchor_idx[m] * DIM + lane * 2);
    float ssa = wave_reduce_sum(fmaf(a.x, a.x, a.y * a.y));
    float rna = (ssa > 0.f) ? rsqrtf(ssa) : 0.f;

    float sp = (float)P_POS;   // the "+1" per positive sample
    float sn = (float)N_NEG;   // the "+1" per negative sample

#pragma unroll
    for (int j = 0; j < P_POS; ++j) {
        int sidx = pos_idx[m * P_POS + j];
        const float2 s =
            *reinterpret_cast<const float2*>(fut + (size_t)sidx * DIM + lane * 2);
        float p = wave_reduce_sum(fmaf(a.x, s.x, a.y * s.y));
        sp += p * rna * rnf[sidx];
    }
#pragma unroll 7
    for (int j = 0; j < N_NEG; ++j) {
        int sidx = neg_idx[m * N_NEG + j];
        const float2 s =
            *reinterpret_cast<const float2*>(fut + (size_t)sidx * DIM + lane * 2);
        float p = wave_reduce_sum(fmaf(a.x, s.x, a.y * s.y));
        sn += p * rna * rnf[sidx];
    }

    if (lane == 0) smem[wave] = -logf(sp / (sp + sn));
    __syncthreads();
    if (threadIdx.x == 0)
        partials[blockIdx.x] = smem[0] + smem[1] + smem[2] + smem[3];
}

__global__ __launch_bounds__(256) void reduce_kernel(const float* __restrict__ partials,
                                                     float* __restrict__ out, int n) {
    __shared__ float smem[256];
    float acc = 0.f;
    for (int i = threadIdx.x; i < n; i += 256) acc += partials[i];
    smem[threadIdx.x] = acc;
    __syncthreads();
#pragma unroll
    for (int s = 128; s > 0; s >>= 1) {
        if ((int)threadIdx.x < s) smem[threadIdx.x] += smem[threadIdx.x + s];
        __syncthreads();
    }
    if (threadIdx.x == 0) out[0] = smem[0];
}

extern "C" void kernel_launch(void* const* d_in, const int* in_sizes, int n_in,
                              void* d_out, int out_size, void* d_ws, size_t ws_size,
                              hipStream_t stream) {
    const float* fut  = (const float*)d_in[0];
    const float* hist = (const float*)d_in[1];
    const int* anchor_idx = (const int*)d_in[2];
    const int* pos_idx    = (const int*)d_in[3];
    const int* neg_idx    = (const int*)d_in[4];

    int N = in_sizes[0] / DIM;   // 66560
    int M = in_sizes[2];         // 16384

    float* rnf = (float*)d_ws;           // N floats
    float* partials = rnf + N;           // M/4 floats

    int norm_blocks = (N + 3) / 4;
    int main_blocks = M / 4;             // 4096 (M is a multiple of 4)

    norms_kernel<<<norm_blocks, 256, 0, stream>>>(fut, rnf, N);
    idloss_kernel<<<main_blocks, 256, 0, stream>>>(fut, hist, anchor_idx, pos_idx,
                                                   neg_idx, rnf, partials);
    reduce_kernel<<<1, 256, 0, stream>>>(partials, (float*)d_out, main_blocks);
}

// Round 2
// 57.505 us; speedup vs baseline: 1.6470x; 1.6470x over previous
//
#include <hip/hip_runtime.h>
#include <math.h>

#define DIM 128
#define P_POS 3
#define N_NEG 63

__device__ __forceinline__ float wave_reduce_sum(float v) {
#pragma unroll
    for (int off = 32; off > 0; off >>= 1) v += __shfl_xor(v, off, 64);
    return v;
}

__device__ __forceinline__ float group16_reduce(float v) {
#pragma unroll
    for (int off = 8; off > 0; off >>= 1) v += __shfl_xor(v, off, 64);
    return v;
}

__device__ __forceinline__ unsigned bf16_rne(float f) {
    unsigned u = __float_as_uint(f);
    u += 0x7fffu + ((u >> 16) & 1u);
    return u >> 16;
}
__device__ __forceinline__ float bflo(unsigned u) { return __uint_as_float(u << 16); }
__device__ __forceinline__ float bfhi(unsigned u) { return __uint_as_float(u & 0xffff0000u); }

__device__ __forceinline__ float dot8(const float4& a0, const float4& a1, const uint4& v,
                                      float acc) {
    acc = fmaf(a0.x, bflo(v.x), acc);
    acc = fmaf(a0.y, bfhi(v.x), acc);
    acc = fmaf(a0.z, bflo(v.y), acc);
    acc = fmaf(a0.w, bfhi(v.y), acc);
    acc = fmaf(a1.x, bflo(v.z), acc);
    acc = fmaf(a1.y, bfhi(v.z), acc);
    acc = fmaf(a1.z, bflo(v.w), acc);
    acc = fmaf(a1.w, bfhi(v.w), acc);
    return acc;
}

// ---- fast path: pre-normalized bf16 ids_fut table -------------------------

// One wave per row: normalize row, pack to bf16 (RNE).
__global__ __launch_bounds__(256) void prep_kernel(const float* __restrict__ fut,
                                                   unsigned* __restrict__ futn,
                                                   int nrows) {
    int wave = threadIdx.x >> 6;
    int lane = threadIdx.x & 63;
    int row = blockIdx.x * 4 + wave;
    if (row >= nrows) return;
    float2 v = *reinterpret_cast<const float2*>(fut + (size_t)row * DIM + lane * 2);
    float ss = wave_reduce_sum(fmaf(v.x, v.x, v.y * v.y));
    float r = (ss > 0.f) ? rsqrtf(ss) : 0.f;
    unsigned lo = bf16_rne(v.x * r);
    unsigned hi = bf16_rne(v.y * r);
    futn[(size_t)row * 64 + lane] = lo | (hi << 16);
}

// One wave per anchor, 4x16-lane groups; no per-sample reduce.
__global__ __launch_bounds__(256) void idloss_bf16_kernel(
    const float* __restrict__ hist, const int* __restrict__ anchor_idx,
    const int* __restrict__ pos_idx, const int* __restrict__ neg_idx,
    const unsigned* __restrict__ futn, float* __restrict__ partials) {
    __shared__ float smem[4];
    int wave = threadIdx.x >> 6;
    int lane = threadIdx.x & 63;
    int m = blockIdx.x * 4 + wave;
    int g = lane >> 4;   // group 0..3
    int t = lane & 15;   // lane-in-group

    // anchor elements [8t, 8t+8), replicated across the 4 groups
    const float4* ap =
        reinterpret_cast<const float4*>(hist + (size_t)anchor_idx[m] * DIM + t * 8);
    float4 a0 = ap[0], a1 = ap[1];
    float ss = a0.x * a0.x;
    ss = fmaf(a0.y, a0.y, ss);
    ss = fmaf(a0.z, a0.z, ss);
    ss = fmaf(a0.w, a0.w, ss);
    ss = fmaf(a1.x, a1.x, ss);
    ss = fmaf(a1.y, a1.y, ss);
    ss = fmaf(a1.z, a1.z, ss);
    ss = fmaf(a1.w, a1.w, ss);
    ss = group16_reduce(ss);
    float rna = (ss > 0.f) ? rsqrtf(ss) : 0.f;
    a0.x *= rna; a0.y *= rna; a0.z *= rna; a0.w *= rna;
    a1.x *= rna; a1.y *= rna; a1.z *= rna; a1.w *= rna;

    float accp = 0.f, accn = 0.f;

    if (g < P_POS) {
        int s = pos_idx[m * P_POS + g];
        uint4 v = *reinterpret_cast<const uint4*>(futn + (size_t)s * 64 + t * 4);
        accp = dot8(a0, a1, v, accp);
    }
#pragma unroll 4
    for (int j = g; j < N_NEG; j += 4) {
        int s = neg_idx[m * N_NEG + j];
        uint4 v = *reinterpret_cast<const uint4*>(futn + (size_t)s * 64 + t * 4);
        accn = dot8(a0, a1, v, accn);
    }

    accp = wave_reduce_sum(accp);
    accn = wave_reduce_sum(accn);
    if (lane == 0) {
        float sp = accp + (float)P_POS;
        float sn = accn + (float)N_NEG;
        smem[wave] = -logf(sp / (sp + sn));
    }
    __syncthreads();
    if (threadIdx.x == 0)
        partials[blockIdx.x] = smem[0] + smem[1] + smem[2] + smem[3];
}

// ---- fallback path (round-1, f32 everywhere) ------------------------------

__global__ __launch_bounds__(256) void norms_kernel(const float* __restrict__ fut,
                                                    float* __restrict__ rnf, int nrows) {
    int wave = threadIdx.x >> 6;
    int lane = threadIdx.x & 63;
    int row = blockIdx.x * 4 + wave;
    if (row >= nrows) return;
    const float2 v = *reinterpret_cast<const float2*>(fut + (size_t)row * DIM + lane * 2);
    float ss = wave_reduce_sum(fmaf(v.x, v.x, v.y * v.y));
    if (lane == 0) rnf[row] = (ss > 0.f) ? rsqrtf(ss) : 0.f;
}

__global__ __launch_bounds__(256) void idloss_kernel(
    const float* __restrict__ fut, const float* __restrict__ hist,
    const int* __restrict__ anchor_idx, const int* __restrict__ pos_idx,
    const int* __restrict__ neg_idx, const float* __restrict__ rnf,
    float* __restrict__ partials) {
    __shared__ float smem[4];
    int wave = threadIdx.x >> 6;
    int lane = threadIdx.x & 63;
    int m = blockIdx.x * 4 + wave;

    const float2 a =
        *reinterpret_cast<const float2*>(hist + (size_t)anchor_idx[m] * DIM + lane * 2);
    float ssa = wave_reduce_sum(fmaf(a.x, a.x, a.y * a.y));
    float rna = (ssa > 0.f) ? rsqrtf(ssa) : 0.f;

    float sp = (float)P_POS;
    float sn = (float)N_NEG;

#pragma unroll
    for (int j = 0; j < P_POS; ++j) {
        int sidx = pos_idx[m * P_POS + j];
        const float2 s =
            *reinterpret_cast<const float2*>(fut + (size_t)sidx * DIM + lane * 2);
        float p = wave_reduce_sum(fmaf(a.x, s.x, a.y * s.y));
        sp += p * rna * rnf[sidx];
    }
#pragma unroll 7
    for (int j = 0; j < N_NEG; ++j) {
        int sidx = neg_idx[m * N_NEG + j];
        const float2 s =
            *reinterpret_cast<const float2*>(fut + (size_t)sidx * DIM + lane * 2);
        float p = wave_reduce_sum(fmaf(a.x, s.x, a.y * s.y));
        sn += p * rna * rnf[sidx];
    }

    if (lane == 0) smem[wave] = -logf(sp / (sp + sn));
    __syncthreads();
    if (threadIdx.x == 0)
        partials[blockIdx.x] = smem[0] + smem[1] + smem[2] + smem[3];
}

__global__ __launch_bounds__(256) void reduce_kernel(const float* __restrict__ partials,
                                                     float* __restrict__ out, int n) {
    __shared__ float smem[256];
    float acc = 0.f;
    for (int i = threadIdx.x; i < n; i += 256) acc += partials[i];
    smem[threadIdx.x] = acc;
    __syncthreads();
#pragma unroll
    for (int s = 128; s > 0; s >>= 1) {
        if ((int)threadIdx.x < s) smem[threadIdx.x] += smem[threadIdx.x + s];
        __syncthreads();
    }
    if (threadIdx.x == 0) out[0] = smem[0];
}

extern "C" void kernel_launch(void* const* d_in, const int* in_sizes, int n_in,
                              void* d_out, int out_size, void* d_ws, size_t ws_size,
                              hipStream_t stream) {
    const float* fut  = (const float*)d_in[0];
    const float* hist = (const float*)d_in[1];
    const int* anchor_idx = (const int*)d_in[2];
    const int* pos_idx    = (const int*)d_in[3];
    const int* neg_idx    = (const int*)d_in[4];

    int N = in_sizes[0] / DIM;   // 66560
    int M = in_sizes[2];         // 16384

    int norm_blocks = (N + 3) / 4;
    int main_blocks = M / 4;     // 4096

    size_t futn_bytes = (size_t)N * 64 * sizeof(unsigned);   // bf16 table, 256 B/row
    size_t need = futn_bytes + (size_t)main_blocks * sizeof(float);

    if (ws_size >= need) {
        unsigned* futn = (unsigned*)d_ws;
        float* partials = (float*)((char*)d_ws + futn_bytes);
        prep_kernel<<<norm_blocks, 256, 0, stream>>>(fut, futn, N);
        idloss_bf16_kernel<<<main_blocks, 256, 0, stream>>>(hist, anchor_idx, pos_idx,
                                                            neg_idx, futn, partials);
        reduce_kernel<<<1, 256, 0, stream>>>(partials, (float*)d_out, main_blocks);
    } else {
        float* rnf = (float*)d_ws;
        float* partials = rnf + N;
        norms_kernel<<<norm_blocks, 256, 0, stream>>>(fut, rnf, N);
        idloss_kernel<<<main_blocks, 256, 0, stream>>>(fut, hist, anchor_idx, pos_idx,
                                                       neg_idx, rnf, partials);
        reduce_kernel<<<1, 256, 0, stream>>>(partials, (float*)d_out, main_blocks);
    }
}

// Round 3
// 35.375 us; speedup vs baseline: 2.6774x; 1.6256x over previous
//
#include <hip/hip_runtime.h>
#include <math.h>

#define DIM 128
#define P_POS 3
#define N_NEG 63
#define SCALE 16.0f

typedef float floatx2 __attribute__((ext_vector_type(2)));

__device__ __forceinline__ float wave_reduce_sum(float v) {
#pragma unroll
    for (int off = 32; off > 0; off >>= 1) v += __shfl_xor(v, off, 64);
    return v;
}
__device__ __forceinline__ float g16_reduce(float v) {
#pragma unroll
    for (int off = 8; off > 0; off >>= 1) v += __shfl_xor(v, off, 64);
    return v;
}
__device__ __forceinline__ float g32_reduce(float v) {
#pragma unroll
    for (int off = 16; off > 0; off >>= 1) v += __shfl_xor(v, off, 64);
    return v;
}

// fp8 e4m3 dequant dot: 8 elements per lane
__device__ __forceinline__ float dot8q(const float4& a0, const float4& a1, uint2 v,
                                       float acc) {
    floatx2 f0 = __builtin_amdgcn_cvt_pk_f32_fp8(v.x, false);
    floatx2 f1 = __builtin_amdgcn_cvt_pk_f32_fp8(v.x, true);
    floatx2 f2 = __builtin_amdgcn_cvt_pk_f32_fp8(v.y, false);
    floatx2 f3 = __builtin_amdgcn_cvt_pk_f32_fp8(v.y, true);
    acc = fmaf(a0.x, f0.x, acc);
    acc = fmaf(a0.y, f0.y, acc);
    acc = fmaf(a0.z, f1.x, acc);
    acc = fmaf(a0.w, f1.y, acc);
    acc = fmaf(a1.x, f2.x, acc);
    acc = fmaf(a1.y, f2.y, acc);
    acc = fmaf(a1.z, f3.x, acc);
    acc = fmaf(a1.w, f3.y, acc);
    return acc;
}

// Normalize each ids_fut row, scale by 16, pack to fp8 e4m3. 2 rows per wave
// (32 lanes/row, 4 elements/lane).
__global__ __launch_bounds__(256) void prep_fp8_kernel(const float* __restrict__ fut,
                                                       unsigned* __restrict__ futq,
                                                       int nrows) {
    int half = threadIdx.x >> 5;   // 0..7
    int l = threadIdx.x & 31;
    int row = blockIdx.x * 8 + half;
    if (row >= nrows) return;
    float4 x = *reinterpret_cast<const float4*>(fut + (size_t)row * DIM + l * 4);
    float ss = x.x * x.x;
    ss = fmaf(x.y, x.y, ss);
    ss = fmaf(x.z, x.z, ss);
    ss = fmaf(x.w, x.w, ss);
    ss = g32_reduce(ss);   // xor offsets <=16 stay within each 32-lane half
    float r = (ss > 0.f) ? rsqrtf(ss) * SCALE : 0.f;
    int w = __builtin_amdgcn_cvt_pk_fp8_f32(x.x * r, x.y * r, 0, false);
    w = __builtin_amdgcn_cvt_pk_fp8_f32(x.z * r, x.w * r, w, true);
    futq[(size_t)row * 32 + l] = (unsigned)w;
}

// One wave per anchor; 4 groups x 16 lanes; all 17 gathers issued in a burst.
__global__ __launch_bounds__(256) void idloss_fp8_kernel(
    const float* __restrict__ hist, const int* __restrict__ anchor_idx,
    const int* __restrict__ pos_idx, const int* __restrict__ neg_idx,
    const uint2* __restrict__ futq, float* __restrict__ partials) {
    __shared__ float smem[4];
    int wave = threadIdx.x >> 6;
    int lane = threadIdx.x & 63;
    int m = blockIdx.x * 4 + wave;
    int g = lane >> 4;   // group 0..3
    int t = lane & 15;   // lane-in-group

    // coalesced index preload: one neg index per lane
    int nidx = (lane < N_NEG) ? neg_idx[m * N_NEG + lane] : 0;
    int pidx = (g < P_POS) ? pos_idx[m * P_POS + g] : 0;

    // anchor elements [8t, 8t+8), replicated across groups
    const float4* ap =
        reinterpret_cast<const float4*>(hist + (size_t)anchor_idx[m] * DIM + t * 8);
    float4 a0 = ap[0], a1 = ap[1];
    float ss = a0.x * a0.x;
    ss = fmaf(a0.y, a0.y, ss);
    ss = fmaf(a0.z, a0.z, ss);
    ss = fmaf(a0.w, a0.w, ss);
    ss = fmaf(a1.x, a1.x, ss);
    ss = fmaf(a1.y, a1.y, ss);
    ss = fmaf(a1.z, a1.z, ss);
    ss = fmaf(a1.w, a1.w, ss);
    ss = g16_reduce(ss);
    float rna = (ss > 0.f) ? rsqrtf(ss) * (1.0f / SCALE) : 0.f;
    a0.x *= rna; a0.y *= rna; a0.z *= rna; a0.w *= rna;
    a1.x *= rna; a1.y *= rna; a1.z *= rna; a1.w *= rna;

    // broadcast neg indices in-register (no memory dependence)
    int js[16];
#pragma unroll
    for (int k = 0; k < 16; ++k) js[k] = __shfl(nidx, 4 * k + g, 64);

    // issue all gathers, then consume
    uint2 vp;
    if (g < P_POS) vp = futq[(size_t)pidx * 16 + t];
    uint2 vs[16];
#pragma unroll
    for (int k = 0; k < 16; ++k)
        if (4 * k + g < N_NEG) vs[k] = futq[(size_t)js[k] * 16 + t];

    float accp = 0.f, accn = 0.f;
    if (g < P_POS) accp = dot8q(a0, a1, vp, accp);
#pragma unroll
    for (int k = 0; k < 16; ++k)
        if (4 * k + g < N_NEG) accn = dot8q(a0, a1, vs[k], accn);

    accp = wave_reduce_sum(accp);
    accn = wave_reduce_sum(accn);
    if (lane == 0) {
        float sp = accp + (float)P_POS;
        float sn = accn + (float)N_NEG;
        smem[wave] = -logf(sp / (sp + sn));
    }
    __syncthreads();
    if (threadIdx.x == 0)
        partials[blockIdx.x] = smem[0] + smem[1] + smem[2] + smem[3];
}

__global__ __launch_bounds__(256) void reduce_kernel(const float* __restrict__ partials,
                                                     float* __restrict__ out, int n) {
    __shared__ float smem[256];
    float acc = 0.f;
    for (int i = threadIdx.x; i < n; i += 256) acc += partials[i];
    smem[threadIdx.x] = acc;
    __syncthreads();
#pragma unroll
    for (int s = 128; s > 0; s >>= 1) {
        if ((int)threadIdx.x < s) smem[threadIdx.x] += smem[threadIdx.x + s];
        __syncthreads();
    }
    if (threadIdx.x == 0) out[0] = smem[0];
}

extern "C" void kernel_launch(void* const* d_in, const int* in_sizes, int n_in,
                              void* d_out, int out_size, void* d_ws, size_t ws_size,
                              hipStream_t stream) {
    const float* fut  = (const float*)d_in[0];
    const float* hist = (const float*)d_in[1];
    const int* anchor_idx = (const int*)d_in[2];
    const int* pos_idx    = (const int*)d_in[3];
    const int* neg_idx    = (const int*)d_in[4];

    int N = in_sizes[0] / DIM;   // 66560
    int M = in_sizes[2];         // 16384

    int prep_blocks = (N + 7) / 8;
    int main_blocks = M / 4;     // 4096

    size_t futq_bytes = (size_t)N * 32 * sizeof(unsigned);   // fp8 table, 128 B/row
    unsigned* futq = (unsigned*)d_ws;
    float* partials = (float*)((char*)d_ws + futq_bytes);

    prep_fp8_kernel<<<prep_blocks, 256, 0, stream>>>(fut, futq, N);
    idloss_fp8_kernel<<<main_blocks, 256, 0, stream>>>(hist, anchor_idx, pos_idx,
                                                       neg_idx, (const uint2*)futq,
                                                       partials);
    reduce_kernel<<<1, 256, 0, stream>>>(partials, (float*)d_out, main_blocks);
}

// Round 4
// 35.112 us; speedup vs baseline: 2.6975x; 1.0075x over previous
//
#include <hip/hip_runtime.h>
#include <math.h>

#define DIM 128
#define P_POS 3
#define N_NEG 63
#define QS 24.0f
#define INVQ2 (1.0f / (QS * QS))
#define SCALE 16.0f   // fp8 fallback scale

typedef float floatx2 __attribute__((ext_vector_type(2)));

#if defined(__has_builtin)
#if __has_builtin(__builtin_amdgcn_sdot8)
#define HAVE_SDOT8 1
#endif
#endif

__device__ __forceinline__ float wave_reduce_sum(float v) {
#pragma unroll
    for (int off = 32; off > 0; off >>= 1) v += __shfl_xor(v, off, 64);
    return v;
}
__device__ __forceinline__ float g16_reduce(float v) {
#pragma unroll
    for (int off = 8; off > 0; off >>= 1) v += __shfl_xor(v, off, 64);
    return v;
}
__device__ __forceinline__ float g32_reduce(float v) {
#pragma unroll
    for (int off = 16; off > 0; off >>= 1) v += __shfl_xor(v, off, 64);
    return v;
}

#if HAVE_SDOT8
// ---------------- int4 path ----------------

// Normalize each ids_fut row, scale by QS, pack to signed 4-bit nibbles.
// 16 lanes per row (8 elems -> 1 dword per lane), 4 rows per wave.
__global__ __launch_bounds__(256) void prep_i4_kernel(const float* __restrict__ fut,
                                                      unsigned* __restrict__ futq,
                                                      int nrows) {
    int row = blockIdx.x * 16 + (threadIdx.x >> 4);
    int t = threadIdx.x & 15;
    if (row >= nrows) return;
    const float4* xp = reinterpret_cast<const float4*>(fut + (size_t)row * DIM + t * 8);
    float4 x0 = xp[0], x1 = xp[1];
    float ss = x0.x * x0.x;
    ss = fmaf(x0.y, x0.y, ss);
    ss = fmaf(x0.z, x0.z, ss);
    ss = fmaf(x0.w, x0.w, ss);
    ss = fmaf(x1.x, x1.x, ss);
    ss = fmaf(x1.y, x1.y, ss);
    ss = fmaf(x1.z, x1.z, ss);
    ss = fmaf(x1.w, x1.w, ss);
    ss = g16_reduce(ss);
    float r = (ss > 0.f) ? rsqrtf(ss) * QS : 0.f;
    float e[8] = {x0.x, x0.y, x0.z, x0.w, x1.x, x1.y, x1.z, x1.w};
    unsigned w = 0;
#pragma unroll
    for (int i = 0; i < 8; ++i) {
        float v = fminf(7.f, fmaxf(-7.f, e[i] * r));
        int q = (int)rintf(v);
        w |= (unsigned)(q & 15) << (4 * i);
    }
    futq[(size_t)row * 16 + t] = w;
}

// One wave per anchor; 4 groups x 16 lanes; per sample: 1 dword load + 1 sdot8.
// Final reduction folded in via last-block pattern.
__global__ __launch_bounds__(256) void idloss_i4_kernel(
    const float* __restrict__ hist, const int* __restrict__ anchor_idx,
    const int* __restrict__ pos_idx, const int* __restrict__ neg_idx,
    const unsigned* __restrict__ futq, float* __restrict__ partials,
    unsigned* __restrict__ counter, float* __restrict__ out, int nblocks) {
    __shared__ float smem[4];
    __shared__ float rbuf[256];
    __shared__ int lastflag;
    int wave = threadIdx.x >> 6;
    int lane = threadIdx.x & 63;
    int m = blockIdx.x * 4 + wave;
    int g = lane >> 4;
    int t = lane & 15;

    int nidx = (lane < N_NEG) ? neg_idx[m * N_NEG + lane] : 0;
    int pidx = (g < P_POS) ? pos_idx[m * P_POS + g] : 0;

    const float4* ap =
        reinterpret_cast<const float4*>(hist + (size_t)anchor_idx[m] * DIM + t * 8);
    float4 a0 = ap[0], a1 = ap[1];
    float ss = a0.x * a0.x;
    ss = fmaf(a0.y, a0.y, ss);
    ss = fmaf(a0.z, a0.z, ss);
    ss = fmaf(a0.w, a0.w, ss);
    ss = fmaf(a1.x, a1.x, ss);
    ss = fmaf(a1.y, a1.y, ss);
    ss = fmaf(a1.z, a1.z, ss);
    ss = fmaf(a1.w, a1.w, ss);
    ss = g16_reduce(ss);
    float ra = (ss > 0.f) ? rsqrtf(ss) * QS : 0.f;

    float e[8] = {a0.x, a0.y, a0.z, a0.w, a1.x, a1.y, a1.z, a1.w};
    unsigned qa = 0;
#pragma unroll
    for (int i = 0; i < 8; ++i) {
        float v = fminf(7.f, fmaxf(-7.f, e[i] * ra));
        int q = (int)rintf(v);
        qa |= (unsigned)(q & 15) << (4 * i);
    }

    int js[16];
#pragma unroll
    for (int k = 0; k < 16; ++k) js[k] = __shfl(nidx, 4 * k + g, 64);

    unsigned vp = 0;
    if (g < P_POS) vp = futq[(size_t)pidx * 16 + t];
    unsigned vs[16];
#pragma unroll
    for (int k = 0; k < 16; ++k)
        if (4 * k + g < N_NEG) vs[k] = futq[(size_t)js[k] * 16 + t];

    int accp = 0, acc0 = 0, acc1 = 0;
    if (g < P_POS) accp = __builtin_amdgcn_sdot8((int)qa, (int)vp, 0, false);
#pragma unroll
    for (int k = 0; k < 16; k += 2) {
        if (4 * k + g < N_NEG) acc0 = __builtin_amdgcn_sdot8((int)qa, (int)vs[k], acc0, false);
        if (4 * (k + 1) + g < N_NEG)
            acc1 = __builtin_amdgcn_sdot8((int)qa, (int)vs[k + 1], acc1, false);
    }

    float accpf = wave_reduce_sum((float)accp * INVQ2);
    float accnf = wave_reduce_sum((float)(acc0 + acc1) * INVQ2);
    if (lane == 0) {
        float sp = accpf + (float)P_POS;
        float sn = accnf + (float)N_NEG;
        smem[wave] = -logf(sp / (sp + sn));
    }
    __syncthreads();
    if (threadIdx.x == 0) {
        partials[blockIdx.x] = smem[0] + smem[1] + smem[2] + smem[3];
        __threadfence();
        unsigned old = atomicAdd(counter, 1u);
        lastflag = (old == (unsigned)(nblocks - 1)) ? 1 : 0;
    }
    __syncthreads();
    if (lastflag) {
        __threadfence();
        float a = 0.f;
        for (int i = threadIdx.x; i < nblocks; i += 256) a += partials[i];
        rbuf[threadIdx.x] = a;
        __syncthreads();
#pragma unroll
        for (int s = 128; s > 0; s >>= 1) {
            if ((int)threadIdx.x < s) rbuf[threadIdx.x] += rbuf[threadIdx.x + s];
            __syncthreads();
        }
        if (threadIdx.x == 0) out[0] = rbuf[0];
    }
}
#endif  // HAVE_SDOT8

// ---------------- fp8 fallback path (round-3, proven) ----------------

__device__ __forceinline__ float dot8q(const float4& a0, const float4& a1, uint2 v,
                                       float acc) {
    floatx2 f0 = __builtin_amdgcn_cvt_pk_f32_fp8(v.x, false);
    floatx2 f1 = __builtin_amdgcn_cvt_pk_f32_fp8(v.x, true);
    floatx2 f2 = __builtin_amdgcn_cvt_pk_f32_fp8(v.y, false);
    floatx2 f3 = __builtin_amdgcn_cvt_pk_f32_fp8(v.y, true);
    acc = fmaf(a0.x, f0.x, acc);
    acc = fmaf(a0.y, f0.y, acc);
    acc = fmaf(a0.z, f1.x, acc);
    acc = fmaf(a0.w, f1.y, acc);
    acc = fmaf(a1.x, f2.x, acc);
    acc = fmaf(a1.y, f2.y, acc);
    acc = fmaf(a1.z, f3.x, acc);
    acc = fmaf(a1.w, f3.y, acc);
    return acc;
}

__global__ __launch_bounds__(256) void prep_fp8_kernel(const float* __restrict__ fut,
                                                       unsigned* __restrict__ futq,
                                                       int nrows) {
    int half = threadIdx.x >> 5;
    int l = threadIdx.x & 31;
    int row = blockIdx.x * 8 + half;
    if (row >= nrows) return;
    float4 x = *reinterpret_cast<const float4*>(fut + (size_t)row * DIM + l * 4);
    float ss = x.x * x.x;
    ss = fmaf(x.y, x.y, ss);
    ss = fmaf(x.z, x.z, ss);
    ss = fmaf(x.w, x.w, ss);
    ss = g32_reduce(ss);
    float r = (ss > 0.f) ? rsqrtf(ss) * SCALE : 0.f;
    int w = __builtin_amdgcn_cvt_pk_fp8_f32(x.x * r, x.y * r, 0, false);
    w = __builtin_amdgcn_cvt_pk_fp8_f32(x.z * r, x.w * r, w, true);
    futq[(size_t)row * 32 + l] = (unsigned)w;
}

__global__ __launch_bounds__(256) void idloss_fp8_kernel(
    const float* __restrict__ hist, const int* __restrict__ anchor_idx,
    const int* __restrict__ pos_idx, const int* __restrict__ neg_idx,
    const uint2* __restrict__ futq, float* __restrict__ partials) {
    __shared__ float smem[4];
    int wave = threadIdx.x >> 6;
    int lane = threadIdx.x & 63;
    int m = blockIdx.x * 4 + wave;
    int g = lane >> 4;
    int t = lane & 15;

    int nidx = (lane < N_NEG) ? neg_idx[m * N_NEG + lane] : 0;
    int pidx = (g < P_POS) ? pos_idx[m * P_POS + g] : 0;

    const float4* ap =
        reinterpret_cast<const float4*>(hist + (size_t)anchor_idx[m] * DIM + t * 8);
    float4 a0 = ap[0], a1 = ap[1];
    float ss = a0.x * a0.x;
    ss = fmaf(a0.y, a0.y, ss);
    ss = fmaf(a0.z, a0.z, ss);
    ss = fmaf(a0.w, a0.w, ss);
    ss = fmaf(a1.x, a1.x, ss);
    ss = fmaf(a1.y, a1.y, ss);
    ss = fmaf(a1.z, a1.z, ss);
    ss = fmaf(a1.w, a1.w, ss);
    ss = g16_reduce(ss);
    float rna = (ss > 0.f) ? rsqrtf(ss) * (1.0f / SCALE) : 0.f;
    a0.x *= rna; a0.y *= rna; a0.z *= rna; a0.w *= rna;
    a1.x *= rna; a1.y *= rna; a1.z *= rna; a1.w *= rna;

    int js[16];
#pragma unroll
    for (int k = 0; k < 16; ++k) js[k] = __shfl(nidx, 4 * k + g, 64);

    uint2 vp;
    if (g < P_POS) vp = futq[(size_t)pidx * 16 + t];
    uint2 vs[16];
#pragma unroll
    for (int k = 0; k < 16; ++k)
        if (4 * k + g < N_NEG) vs[k] = futq[(size_t)js[k] * 16 + t];

    float accp = 0.f, accn = 0.f;
    if (g < P_POS) accp = dot8q(a0, a1, vp, accp);
#pragma unroll
    for (int k = 0; k < 16; ++k)
        if (4 * k + g < N_NEG) accn = dot8q(a0, a1, vs[k], accn);

    accp = wave_reduce_sum(accp);
    accn = wave_reduce_sum(accn);
    if (lane == 0) {
        float sp = accp + (float)P_POS;
        float sn = accn + (float)N_NEG;
        smem[wave] = -logf(sp / (sp + sn));
    }
    __syncthreads();
    if (threadIdx.x == 0)
        partials[blockIdx.x] = smem[0] + smem[1] + smem[2] + smem[3];
}

__global__ __launch_bounds__(256) void reduce_kernel(const float* __restrict__ partials,
                                                     float* __restrict__ out, int n) {
    __shared__ float smem[256];
    float acc = 0.f;
    for (int i = threadIdx.x; i < n; i += 256) acc += partials[i];
    smem[threadIdx.x] = acc;
    __syncthreads();
#pragma unroll
    for (int s = 128; s > 0; s >>= 1) {
        if ((int)threadIdx.x < s) smem[threadIdx.x] += smem[threadIdx.x + s];
        __syncthreads();
    }
    if (threadIdx.x == 0) out[0] = smem[0];
}

extern "C" void kernel_launch(void* const* d_in, const int* in_sizes, int n_in,
                              void* d_out, int out_size, void* d_ws, size_t ws_size,
                              hipStream_t stream) {
    const float* fut  = (const float*)d_in[0];
    const float* hist = (const float*)d_in[1];
    const int* anchor_idx = (const int*)d_in[2];
    const int* pos_idx    = (const int*)d_in[3];
    const int* neg_idx    = (const int*)d_in[4];

    int N = in_sizes[0] / DIM;   // 66560
    int M = in_sizes[2];         // 16384
    int main_blocks = M / 4;     // 4096

#if HAVE_SDOT8
    size_t futq_bytes = (size_t)N * 16 * sizeof(unsigned);   // int4 table, 64 B/row
    unsigned* futq = (unsigned*)d_ws;
    float* partials = (float*)((char*)d_ws + futq_bytes);
    unsigned* counter = (unsigned*)(partials + main_blocks);

    hipMemsetAsync(counter, 0, sizeof(unsigned), stream);
    int prep_blocks = (N + 15) / 16;
    prep_i4_kernel<<<prep_blocks, 256, 0, stream>>>(fut, futq, N);
    idloss_i4_kernel<<<main_blocks, 256, 0, stream>>>(hist, anchor_idx, pos_idx, neg_idx,
                                                      futq, partials, counter,
                                                      (float*)d_out, main_blocks);
#else
    size_t futq_bytes = (size_t)N * 32 * sizeof(unsigned);   // fp8 table, 128 B/row
    unsigned* futq = (unsigned*)d_ws;
    float* partials = (float*)((char*)d_ws + futq_bytes);

    int prep_blocks = (N + 7) / 8;
    prep_fp8_kernel<<<prep_blocks, 256, 0, stream>>>(fut, futq, N);
    idloss_fp8_kernel<<<main_blocks, 256, 0, stream>>>(hist, anchor_idx, pos_idx,
                                                       neg_idx, (const uint2*)futq,
                                                       partials);
    reduce_kernel<<<1, 256, 0, stream>>>(partials, (float*)d_out, main_blocks);
#endif
}